// Round 13
// baseline (22.627 us; speedup 1.0000x reference)
//
#include <hip/hip_runtime.h>

// out[b,h] = (X X^T) X == X (X^T X) per head; X = x[b,h] : [2048 x 64] fp32.
// MFMA bf16 (fp32 accumulate), 3 dispatches:
//  K1 (512 blocks x 512 threads, 128-row chunks, 16 waves/CU):
//     global->reg (4 rows x 4 cols/thread) -> f2bf -> transposed swizzled XT;
//     8 MFMA/wave Gram (K=128); packed bf16 partial store; ALSO emits the
//     bf16 row-major pre-swizzled X-image (m173) for K2b's linear DMA.
//  K2a (128 blocks): fixed-order fp32 reduce of 16 bf16 partials -> G;
//     emits pre-swizzled bf16 G image.
//  K2b (1024 blocks x 256 threads, 64-row tiles, 4 blocks/CU): DMA X-image
//     (8 KB) + G (8 KB); ONE barrier; 8 MFMA/wave; out. No converts at all.
// C/D layout per m89: col = lane&15, row = (lane>>4)*4 + reg.

#define TDIM 2048
#define DDIM 64
#define NHEADS 32
#define NCH 16                                    // 128-row chunks per head

typedef float f4 __attribute__((ext_vector_type(4)));
typedef float f32x4 __attribute__((ext_vector_type(4)));
typedef short bf16x8 __attribute__((ext_vector_type(8)));
typedef short s4 __attribute__((ext_vector_type(4)));

// Async global->LDS DMA, 16 B/lane. LDS dest wave-uniform; lane l -> dest+l*16.
__device__ __forceinline__ void async_copy16(const void* g, void* l) {
    __builtin_amdgcn_global_load_lds(
        (const __attribute__((address_space(1))) void*)g,
        (__attribute__((address_space(3))) void*)l, 16, 0, 0);
}

// f32 -> bf16 bits (RNE) and back.
__device__ __forceinline__ short f2bf(float f) {
    unsigned u = __builtin_bit_cast(unsigned, f);
    unsigned r = (u + 0x7fffu + ((u >> 16) & 1u)) >> 16;
    return (short)r;
}
__device__ __forceinline__ float bf2f(short s) {
    return __builtin_bit_cast(float, ((unsigned)(unsigned short)s) << 16);
}

// Swizzled fragment pointer: row-major bf16 tile (rowlen shorts/row); byte
// offset within row = (kelem*2) ^ ((row&7)<<4). 16 B alignment preserved.
__device__ __forceinline__ const bf16x8* fragp(const short* base, int row,
                                               int rowlen, int kelem) {
    const char* p = (const char*)(base + row * rowlen);
    return (const bf16x8*)(p + ((kelem * 2) ^ ((row & 7) << 4)));
}

// ---------------- K1: partial Gram + X-image emission ----------------
__global__ __launch_bounds__(512) void k1_gram(const float* __restrict__ x,
                                               short* __restrict__ part,
                                               short* __restrict__ xbf) {
    __shared__ __align__(16) short XT[64 * 128];  // 16 KB transposed swz bf16

    const int b    = blockIdx.x;        // 0..511
    const int tid  = threadIdx.x;       // 0..511
    const int lane = tid & 63;
    const int w    = tid >> 6;          // 0..7
    const int head = b >> 4, ch = b & 15;

    const float* xh = x + ((size_t)head * TDIM + ch * 128) * DDIM;

    // Thread owns rows r0..r0+3 x cols c4..c4+3.
    const int rg = tid >> 4;            // 0..31
    const int cg = tid & 15;
    const int r0 = rg * 4, c4 = cg * 4;

    f4 v[4];
#pragma unroll
    for (int k = 0; k < 4; ++k)
        v[k] = *reinterpret_cast<const f4*>(xh + (size_t)(r0 + k) * DDIM + c4);

    short pk[4][4];                     // [row k][col j] bf16
#pragma unroll
    for (int k = 0; k < 4; ++k)
#pragma unroll
        for (int j = 0; j < 4; ++j) pk[k][j] = f2bf(v[k][j]);

    // (a) transposed swizzled XT: per column j, 4 t-contiguous shorts (b64).
#pragma unroll
    for (int j = 0; j < 4; ++j) {
        const int c = c4 + j;
        s4 t4;
#pragma unroll
        for (int k = 0; k < 4; ++k) t4[k] = pk[k][j];
        *(s4*)((char*)XT + c * 256 + ((2 * r0) ^ ((c & 7) << 4))) = t4;
    }

    // (b) X-image: row-major bf16, pre-swizzled rows of 128 B.
    {
        char* img = (char*)xbf + (size_t)head * 262144;  // 2048*128 B per head
#pragma unroll
        for (int k = 0; k < 4; ++k) {
            const int R = ch * 128 + r0 + k;
            s4 t4;
#pragma unroll
            for (int j = 0; j < 4; ++j) t4[j] = pk[k][j];
            *(s4*)(img + (size_t)R * 128 + ((2 * c4) ^ ((R & 7) << 4))) = t4;
        }
    }
    __syncthreads();

    // Gram MFMA over K=128: wave w owns i_tile = w>>1, j_tiles {(w&1)*2+d}.
    const int li = lane & 15, g = lane >> 4;
    const int i_tile = w >> 1, j0 = (w & 1) * 2;

    f32x4 acc[2];
#pragma unroll
    for (int d = 0; d < 2; ++d) acc[d] = (f32x4){0.f, 0.f, 0.f, 0.f};

#pragma unroll
    for (int k0 = 0; k0 < 128; k0 += 32) {
        bf16x8 af, bv[2];
        af = *fragp(XT, i_tile * 16 + li, 128, k0 + 8 * g);
        bv[0] = *fragp(XT, (j0 + 0) * 16 + li, 128, k0 + 8 * g);
        bv[1] = *fragp(XT, (j0 + 1) * 16 + li, 128, k0 + 8 * g);
#pragma unroll
        for (int d = 0; d < 2; ++d)
            acc[d] = __builtin_amdgcn_mfma_f32_16x16x32_bf16(
                af, bv[d], acc[d], 0, 0, 0);
    }

    // Packed bf16 partial store: s4 index f = (w*2+d)*64 + lane.
    short* pp = part + (size_t)b * 4096;
#pragma unroll
    for (int d = 0; d < 2; ++d) {
        s4 o;
#pragma unroll
        for (int q = 0; q < 4; ++q) o[q] = f2bf(acc[d][q]);
        *(s4*)(pp + (((w * 2 + d) * 64 + lane) << 2)) = o;
    }
}

// ---------------- K2a: reduce packed partials -> pre-swizzled bf16 G --------
__global__ __launch_bounds__(256) void k2a_reduce(const short* __restrict__ part,
                                                  short* __restrict__ gbf) {
    const int b    = blockIdx.x;        // 0..127
    const int tid  = threadIdx.x;
    const int head = b >> 2, quarter = b & 3;

    const int f = quarter * 256 + tid;  // s4 index within chunk, 0..1023
    const short* ph = part + (size_t)head * NCH * 4096 + (f << 2);

    float s[4] = {0.f, 0.f, 0.f, 0.f};
#pragma unroll
    for (int c = 0; c < NCH; ++c) {
        const s4 v = *reinterpret_cast<const s4*>(ph + (size_t)c * 4096);
#pragma unroll
        for (int q = 0; q < 4; ++q) s[q] += bf2f(v[q]);
    }

    // decode f = (w*2+d)*64+lane -> (i,j); store swizzled G image.
    const int lane = f & 63, wd = f >> 6;
    const int w = wd >> 1, d = wd & 1;
    const int g = lane >> 4, li = lane & 15;
    const int i_tile = w >> 1, j_tile = (w & 1) * 2 + d;
    const int j = j_tile * 16 + li;
    char* gb = (char*)gbf + (size_t)head * 8192;
#pragma unroll
    for (int q = 0; q < 4; ++q) {
        const int i = i_tile * 16 + g * 4 + q;
        *(short*)(gb + i * 128 + ((2 * j) ^ ((i & 7) << 4))) = f2bf(s[q]);
    }
}

// ---------------- K2b: out = X*G via MFMA (pure DMA + MFMA) ---------------
__global__ __launch_bounds__(256) void k2b_xg(float* __restrict__ out,
                                              const short* __restrict__ xbf,
                                              const short* __restrict__ gbf) {
    __shared__ __align__(16) short Xb[4096];      // 8 KB bf16 swz image tile
    __shared__ __align__(16) short Gb[4096];      // 8 KB bf16 G swz

    const int b    = blockIdx.x;        // 0..1023
    const int tid  = threadIdx.x;
    const int lane = tid & 63;
    const int w    = tid >> 6;
    const int head = b >> 5, ch = b & 31;

    {   // DMA X-image tile + G image, both linear.
        const short* gx = xbf + (size_t)head * 131072 + ch * 4096 +
                          w * 1024 + lane * 8;
        const short* gg = gbf + (size_t)head * 4096 + w * 1024 + lane * 8;
#pragma unroll
        for (int it = 0; it < 2; ++it) {
            async_copy16(gx + it * 512, Xb + w * 1024 + it * 512);
            async_copy16(gg + it * 512, Gb + w * 1024 + it * 512);
        }
    }
    __syncthreads();   // compiler drains vmcnt before s_barrier

    // MFMA: wave w owns row-tile w (16 rows) x 4 col-tiles, K=64.
    const int li = lane & 15, g = lane >> 4;

    f32x4 acc[4];
#pragma unroll
    for (int d = 0; d < 4; ++d) acc[d] = (f32x4){0.f, 0.f, 0.f, 0.f};

#pragma unroll
    for (int k0 = 0; k0 < 64; k0 += 32) {
        bf16x8 af, bv[4];
        af = *fragp(Xb, w * 16 + li, 64, k0 + 8 * g);
#pragma unroll
        for (int d = 0; d < 4; ++d)
            bv[d] = *fragp(Gb, d * 16 + li, 64, k0 + 8 * g);
#pragma unroll
        for (int d = 0; d < 4; ++d)
            acc[d] = __builtin_amdgcn_mfma_f32_16x16x32_bf16(
                af, bv[d], acc[d], 0, 0, 0);
    }

    float* oh = out + ((size_t)head * TDIM + ch * 64) * DDIM;
#pragma unroll
    for (int d = 0; d < 4; ++d)
#pragma unroll
        for (int q = 0; q < 4; ++q)
            oh[(w * 16 + g * 4 + q) * 64 + d * 16 + li] = acc[d][q];
}

extern "C" void kernel_launch(void* const* d_in, const int* in_sizes, int n_in,
                              void* d_out, int out_size, void* d_ws, size_t ws_size,
                              hipStream_t stream) {
    const float* x = (const float*)d_in[0];
    float* out  = (float*)d_out;
    short* part = (short*)d_ws;                          // 512*8 KB = 4 MB
    short* gbf  = part + (size_t)512 * 4096;             // 256 KB
    short* xbf  = gbf + (size_t)NHEADS * 4096;           // 8.4 MB image

    k1_gram<<<NHEADS * NCH, 512, 0, stream>>>(x, part, xbf);
    k2a_reduce<<<128, 256, 0, stream>>>(part, gbf);
    k2b_xg<<<NHEADS * 32, 256, 0, stream>>>(out, xbf, gbf);
}

// Round 14
// 20.943 us; speedup vs baseline: 1.0804x; 1.0804x over previous
//
#include <hip/hip_runtime.h>

// out[b,h] = (X X^T) X == X (X^T X) per head; X = x[b,h] : [2048 x 64] fp32.
// MFMA bf16 (fp32 accumulate), 3 dispatches, occupancy-tuned:
//  K1 (1024 blocks, 64-row chunks, 4 blocks/CU): global->reg (4 rows x 4
//     cols/thread), f2bf, transpose via b64 writes into swizzled XT (8 KB);
//     8 MFMA/wave (2x2 quad, K=64); packed bf16 partial store (32/head).
//  K2a (128 blocks): fixed-order fp32 reduce of 32 bf16 partials -> G;
//     emits PRE-SWIZZLED bf16 G image (m173) for K2b's linear DMA.
//  K2b (1024 blocks, 64-row tiles): reg-stage f32 X + DMA G concurrently;
//     one barrier; 8 MFMA/wave; out.  (unchanged from R12)
// C/D layout per m89: col = lane&15, row = (lane>>4)*4 + reg.

#define TDIM 2048
#define DDIM 64
#define NHEADS 32
#define NCH 32                                    // 64-row chunks per head

typedef float f4 __attribute__((ext_vector_type(4)));
typedef float f32x4 __attribute__((ext_vector_type(4)));
typedef short bf16x8 __attribute__((ext_vector_type(8)));
typedef short s4 __attribute__((ext_vector_type(4)));

// Async global->LDS DMA, 16 B/lane. LDS dest wave-uniform; lane l -> dest+l*16.
__device__ __forceinline__ void async_copy16(const void* g, void* l) {
    __builtin_amdgcn_global_load_lds(
        (const __attribute__((address_space(1))) void*)g,
        (__attribute__((address_space(3))) void*)l, 16, 0, 0);
}

// f32 -> bf16 bits (RNE) and back.
__device__ __forceinline__ short f2bf(float f) {
    unsigned u = __builtin_bit_cast(unsigned, f);
    unsigned r = (u + 0x7fffu + ((u >> 16) & 1u)) >> 16;
    return (short)r;
}
__device__ __forceinline__ float bf2f(short s) {
    return __builtin_bit_cast(float, ((unsigned)(unsigned short)s) << 16);
}

// Swizzled fragment pointer: row-major bf16 tile (rowlen shorts/row); byte
// offset within row = (kelem*2) ^ ((row&7)<<4). 16 B alignment preserved.
__device__ __forceinline__ const bf16x8* fragp(const short* base, int row,
                                               int rowlen, int kelem) {
    const char* p = (const char*)(base + row * rowlen);
    return (const bf16x8*)(p + ((kelem * 2) ^ ((row & 7) << 4)));
}

// ---------------- K1: partial Gram (64-row chunks) ----------------
__global__ __launch_bounds__(256) void k1_gram(const float* __restrict__ x,
                                               short* __restrict__ part) {
    __shared__ __align__(16) short XT[64 * 64];   // 8 KB transposed swz bf16

    const int b    = blockIdx.x;        // 0..1023
    const int tid  = threadIdx.x;
    const int lane = tid & 63;
    const int w    = tid >> 6;
    const int head = b >> 5, ch = b & 31;

    const float* xh = x + ((size_t)head * TDIM + ch * 64) * DDIM;

    // Thread owns rows r0..r0+3 x cols c4..c4+3 of the 64x64 tile.
    const int rg = tid >> 4, cg = tid & 15;
    const int r0 = rg * 4, c4 = cg * 4;

    f4 v[4];
#pragma unroll
    for (int k = 0; k < 4; ++k)
        v[k] = *reinterpret_cast<const f4*>(xh + (size_t)(r0 + k) * DDIM + c4);

    // Transpose: per column j, 4 t-contiguous bf16 as one b64 write.
#pragma unroll
    for (int j = 0; j < 4; ++j) {
        s4 t4;
#pragma unroll
        for (int k = 0; k < 4; ++k) t4[k] = f2bf(v[k][j]);
        const int c = c4 + j;
        *(s4*)((char*)XT + c * 128 + ((2 * r0) ^ ((c & 7) << 4))) = t4;
    }
    __syncthreads();

    // Gram MFMA over K=64: wave w owns 2x2 quad of 16x16 G tiles.
    const int li = lane & 15, g = lane >> 4;
    const int iq0 = (w >> 1) * 2, jq0 = (w & 1) * 2;

    f32x4 acc[2][2];
#pragma unroll
    for (int a = 0; a < 2; ++a)
#pragma unroll
        for (int q = 0; q < 2; ++q) acc[a][q] = (f32x4){0.f, 0.f, 0.f, 0.f};

#pragma unroll
    for (int k0 = 0; k0 < 64; k0 += 32) {
        bf16x8 af[2], bv[2];
        af[0] = *fragp(XT, (iq0 + 0) * 16 + li, 64, k0 + 8 * g);
        af[1] = *fragp(XT, (iq0 + 1) * 16 + li, 64, k0 + 8 * g);
        bv[0] = *fragp(XT, (jq0 + 0) * 16 + li, 64, k0 + 8 * g);
        bv[1] = *fragp(XT, (jq0 + 1) * 16 + li, 64, k0 + 8 * g);
#pragma unroll
        for (int a = 0; a < 2; ++a)
#pragma unroll
            for (int q = 0; q < 2; ++q)
                acc[a][q] = __builtin_amdgcn_mfma_f32_16x16x32_bf16(
                    af[a], bv[q], acc[a][q], 0, 0, 0);
    }

    // Packed bf16 partial store: s4 index f = ((w*2+a)*2+d)*64 + lane.
    short* pp = part + (size_t)b * 4096;
#pragma unroll
    for (int a = 0; a < 2; ++a)
#pragma unroll
        for (int d = 0; d < 2; ++d) {
            s4 o;
#pragma unroll
            for (int q = 0; q < 4; ++q) o[q] = f2bf(acc[a][d][q]);
            *(s4*)(pp + ((((w * 2 + a) * 2 + d) * 64 + lane) << 2)) = o;
        }
}

// ---------------- K2a: reduce packed partials -> pre-swizzled bf16 G --------
__global__ __launch_bounds__(256) void k2a_reduce(const short* __restrict__ part,
                                                  short* __restrict__ gbf) {
    const int b    = blockIdx.x;        // 0..127
    const int tid  = threadIdx.x;
    const int head = b >> 2, quarter = b & 3;

    const int f = quarter * 256 + tid;  // s4 index within chunk, 0..1023
    const short* ph = part + (size_t)head * NCH * 4096 + (f << 2);

    float s[4] = {0.f, 0.f, 0.f, 0.f};
#pragma unroll
    for (int c = 0; c < NCH; ++c) {
        const s4 v = *reinterpret_cast<const s4*>(ph + (size_t)c * 4096);
#pragma unroll
        for (int q = 0; q < 4; ++q) s[q] += bf2f(v[q]);
    }

    // decode f = ((w*2+a)*2+d)*64+lane -> (i,j); store swizzled G image.
    const int lane = f & 63, wad = f >> 6;
    const int w = wad >> 2, a = (wad >> 1) & 1, d = wad & 1;
    const int g = lane >> 4, li = lane & 15;
    const int i_tile = (w >> 1) * 2 + a, j_tile = (w & 1) * 2 + d;
    const int j = j_tile * 16 + li;
    char* gb = (char*)gbf + (size_t)head * 8192;
#pragma unroll
    for (int q = 0; q < 4; ++q) {
        const int i = i_tile * 16 + g * 4 + q;
        *(short*)(gb + i * 128 + ((2 * j) ^ ((i & 7) << 4))) = f2bf(s[q]);
    }
}

// ---------------- K2b: out = X*G via MFMA (reg-staged X, 1 barrier) ---------
__global__ __launch_bounds__(256) void k2b_xg(const float* __restrict__ x,
                                              float* __restrict__ out,
                                              const short* __restrict__ gbf) {
    __shared__ __align__(16) short Xb[4096];      // 8 KB bf16 swz
    __shared__ __align__(16) short Gb[4096];      // 8 KB bf16 G swz

    const int b    = blockIdx.x;        // 0..1023
    const int tid  = threadIdx.x;
    const int lane = tid & 63;
    const int w    = tid >> 6;
    const int head = b >> 5, ch = b & 31;

    {   // DMA bf16 G image (8 KB, linear; pre-swizzled at write time)
        const short* gg = gbf + (size_t)head * 4096 + w * 1024 + lane * 8;
        short* lg = Gb + w * 1024;
#pragma unroll
        for (int it = 0; it < 2; ++it)
            async_copy16(gg + it * 512, lg + it * 512);
    }

    // Reg-stage X tile (64x64 f32), convert, swizzled LDS writes.
    const float* xh = x + ((size_t)head * TDIM + ch * 64) * DDIM;
#pragma unroll
    for (int e = 0; e < 4; ++e) {
        const int i4 = e * 256 + tid;            // f4 index in 64x64 tile
        const int r  = i4 >> 4;
        const int c4 = (i4 & 15) << 2;
        const f4 v = *reinterpret_cast<const f4*>(xh + (size_t)i4 * 4);
        s4 pk;
        pk[0] = f2bf(v[0]); pk[1] = f2bf(v[1]);
        pk[2] = f2bf(v[2]); pk[3] = f2bf(v[3]);
        *(s4*)((char*)Xb + r * 128 + ((2 * c4) ^ ((r & 7) << 4))) = pk;
    }
    __syncthreads();   // drains G DMA (vmcnt) + Xb writes (lgkmcnt)

    // MFMA: wave w owns row-tile w (16 rows) x 4 col-tiles, K=64.
    const int li = lane & 15, g = lane >> 4;

    f32x4 acc[4];
#pragma unroll
    for (int d = 0; d < 4; ++d) acc[d] = (f32x4){0.f, 0.f, 0.f, 0.f};

#pragma unroll
    for (int k0 = 0; k0 < 64; k0 += 32) {
        bf16x8 af, bv[4];
        af = *fragp(Xb, w * 16 + li, 64, k0 + 8 * g);
#pragma unroll
        for (int d = 0; d < 4; ++d)
            bv[d] = *fragp(Gb, d * 16 + li, 64, k0 + 8 * g);
#pragma unroll
        for (int d = 0; d < 4; ++d)
            acc[d] = __builtin_amdgcn_mfma_f32_16x16x32_bf16(
                af, bv[d], acc[d], 0, 0, 0);
    }

    float* oh = out + ((size_t)head * TDIM + ch * 64) * DDIM;
#pragma unroll
    for (int d = 0; d < 4; ++d)
#pragma unroll
        for (int q = 0; q < 4; ++q)
            oh[(w * 16 + g * 4 + q) * 64 + d * 16 + li] = acc[d][q];
}

extern "C" void kernel_launch(void* const* d_in, const int* in_sizes, int n_in,
                              void* d_out, int out_size, void* d_ws, size_t ws_size,
                              hipStream_t stream) {
    const float* x = (const float*)d_in[0];
    float* out  = (float*)d_out;
    short* part = (short*)d_ws;                          // 1024*8 KB = 8.4 MB
    short* gbf  = part + (size_t)1024 * 4096;            // 256 KB

    k1_gram<<<NHEADS * NCH, 256, 0, stream>>>(x, part);
    k2a_reduce<<<128, 256, 0, stream>>>(part, gbf);
    k2b_xg<<<NHEADS * 32, 256, 0, stream>>>(x, out, gbf);
}

// Round 15
// 18.442 us; speedup vs baseline: 1.2269x; 1.1356x over previous
//
#include <hip/hip_runtime.h>

// out[b,h] = (X X^T) X == X (X^T X) per head; X = x[b,h] : [2048 x 64] fp32.
// MFMA bf16 (fp32 accumulate), 3 dispatches (R12 skeleton; K2b widened):
//  K1 (512 blocks x 256 thr, 128-row chunks): global->reg (8 rows x 4 cols /
//     thread), f2bf, transpose via ds_write_b128 into swizzled XT (16 KB);
//     16 MFMA/wave Gram (K=128); packed bf16 partial store (16/head).
//  K2a (128 blocks): fixed-order fp32 reduce of 16 bf16 partials -> G;
//     emits PRE-SWIZZLED bf16 G image (m173) for K2b's linear DMA.
//  K2b (512 blocks x 512 thr, 128-row tiles): reg-stage f32 X + DMA G
//     concurrently; one barrier; 8 MFMA/wave; out.
// C/D layout per m89: col = lane&15, row = (lane>>4)*4 + reg.

#define TDIM 2048
#define DDIM 64
#define NHEADS 32
#define NCH 16                                    // 128-row chunks per head

typedef float f4 __attribute__((ext_vector_type(4)));
typedef float f32x4 __attribute__((ext_vector_type(4)));
typedef short bf16x8 __attribute__((ext_vector_type(8)));
typedef short s4 __attribute__((ext_vector_type(4)));

// Async global->LDS DMA, 16 B/lane. LDS dest wave-uniform; lane l -> dest+l*16.
__device__ __forceinline__ void async_copy16(const void* g, void* l) {
    __builtin_amdgcn_global_load_lds(
        (const __attribute__((address_space(1))) void*)g,
        (__attribute__((address_space(3))) void*)l, 16, 0, 0);
}

// f32 -> bf16 bits (RNE) and back.
__device__ __forceinline__ short f2bf(float f) {
    unsigned u = __builtin_bit_cast(unsigned, f);
    unsigned r = (u + 0x7fffu + ((u >> 16) & 1u)) >> 16;
    return (short)r;
}
__device__ __forceinline__ float bf2f(short s) {
    return __builtin_bit_cast(float, ((unsigned)(unsigned short)s) << 16);
}

// Swizzled fragment pointer: row-major bf16 tile (rowlen shorts/row); byte
// offset within row = (kelem*2) ^ ((row&7)<<4). 16 B alignment preserved.
__device__ __forceinline__ const bf16x8* fragp(const short* base, int row,
                                               int rowlen, int kelem) {
    const char* p = (const char*)(base + row * rowlen);
    return (const bf16x8*)(p + ((kelem * 2) ^ ((row & 7) << 4)));
}

// ---------------- K1: partial Gram (identical to R12) ----------------
__global__ __launch_bounds__(256) void k1_gram(const float* __restrict__ x,
                                               short* __restrict__ part) {
    __shared__ __align__(16) short XT[64 * 128];  // 16 KB transposed swz bf16

    const int b    = blockIdx.x;        // 0..511
    const int tid  = threadIdx.x;
    const int lane = tid & 63;
    const int w    = tid >> 6;
    const int head = b >> 4, ch = b & 15;

    const float* xh = x + ((size_t)head * TDIM + ch * 128) * DDIM;

    // Thread owns rows r0..r0+7 x cols c4..c4+3.
    const int rg = tid >> 4, cg = tid & 15;
    const int r0 = rg * 8, c4 = cg * 4;

    f4 v[8];
#pragma unroll
    for (int k = 0; k < 8; ++k)
        v[k] = *reinterpret_cast<const f4*>(xh + (size_t)(r0 + k) * DDIM + c4);

    // Transpose: one b128 (8 t-contiguous bf16) per column.
#pragma unroll
    for (int j = 0; j < 4; ++j) {
        bf16x8 pk;
#pragma unroll
        for (int k = 0; k < 8; ++k) pk[k] = f2bf(v[k][j]);
        const int c = c4 + j;
        *(bf16x8*)((char*)XT + c * 256 + ((2 * r0) ^ ((c & 7) << 4))) = pk;
    }
    __syncthreads();

    // Gram MFMA over K=128: wave w owns 2x2 quad of 16x16 G tiles.
    const int li = lane & 15, g = lane >> 4;
    const int iq0 = (w >> 1) * 2, jq0 = (w & 1) * 2;

    f32x4 acc[2][2];
#pragma unroll
    for (int a = 0; a < 2; ++a)
#pragma unroll
        for (int q = 0; q < 2; ++q) acc[a][q] = (f32x4){0.f, 0.f, 0.f, 0.f};

#pragma unroll
    for (int k0 = 0; k0 < 128; k0 += 32) {
        bf16x8 af[2], bv[2];
        af[0] = *fragp(XT, (iq0 + 0) * 16 + li, 128, k0 + 8 * g);
        af[1] = *fragp(XT, (iq0 + 1) * 16 + li, 128, k0 + 8 * g);
        bv[0] = *fragp(XT, (jq0 + 0) * 16 + li, 128, k0 + 8 * g);
        bv[1] = *fragp(XT, (jq0 + 1) * 16 + li, 128, k0 + 8 * g);
#pragma unroll
        for (int a = 0; a < 2; ++a)
#pragma unroll
            for (int q = 0; q < 2; ++q)
                acc[a][q] = __builtin_amdgcn_mfma_f32_16x16x32_bf16(
                    af[a], bv[q], acc[a][q], 0, 0, 0);
    }

    // Packed bf16 partial store: s4 index f = ((w*2+a)*2+d)*64 + lane.
    short* pp = part + (size_t)b * 4096;
#pragma unroll
    for (int a = 0; a < 2; ++a)
#pragma unroll
        for (int d = 0; d < 2; ++d) {
            s4 pk;
#pragma unroll
            for (int q = 0; q < 4; ++q) pk[q] = f2bf(acc[a][d][q]);
            *(s4*)(pp + ((((w * 2 + a) * 2 + d) * 64 + lane) << 2)) = pk;
        }
}

// ---------------- K2a: reduce packed partials -> pre-swizzled bf16 G --------
// (identical to R12)
__global__ __launch_bounds__(256) void k2a_reduce(const short* __restrict__ part,
                                                  short* __restrict__ gbf) {
    const int b    = blockIdx.x;        // 0..127
    const int tid  = threadIdx.x;
    const int head = b >> 2, quarter = b & 3;

    const int f = quarter * 256 + tid;  // s4 index within chunk, 0..1023
    const short* ph = part + (size_t)head * NCH * 4096 + (f << 2);

    float s[4] = {0.f, 0.f, 0.f, 0.f};
#pragma unroll
    for (int c = 0; c < NCH; ++c) {
        const s4 v = *reinterpret_cast<const s4*>(ph + (size_t)c * 4096);
#pragma unroll
        for (int q = 0; q < 4; ++q) s[q] += bf2f(v[q]);
    }

    // decode f -> (w,a,d,lane) -> (i,j) and store swizzled G image.
    const int lane = f & 63, wad = f >> 6;
    const int w = wad >> 2, a = (wad >> 1) & 1, d = wad & 1;
    const int g = lane >> 4, li = lane & 15;
    const int iq0 = (w >> 1) * 2, jq0 = (w & 1) * 2;
    const int j = (jq0 + d) * 16 + li;
    char* gb = (char*)gbf + (size_t)head * 8192;
#pragma unroll
    for (int q = 0; q < 4; ++q) {
        const int i = (iq0 + a) * 16 + g * 4 + q;
        *(short*)(gb + i * 128 + ((2 * j) ^ ((i & 7) << 4))) = f2bf(s[q]);
    }
}

// ---------------- K2b: out = X*G via MFMA (512 thr, 128-row tiles) ----------
__global__ __launch_bounds__(512) void k2b_xg(const float* __restrict__ x,
                                              float* __restrict__ out,
                                              const short* __restrict__ gbf) {
    __shared__ __align__(16) short Xb[8192];      // 16 KB bf16 swz (128x64)
    __shared__ __align__(16) short Gb[4096];      // 8 KB bf16 G swz

    const int b    = blockIdx.x;        // 0..511
    const int tid  = threadIdx.x;       // 0..511
    const int lane = tid & 63;
    const int w    = tid >> 6;          // 0..7
    const int head = b >> 4, ch = b & 15;

    {   // DMA bf16 G image (8 KB, linear; pre-swizzled at write time)
        const short* gg = gbf + (size_t)head * 4096 + w * 512 + lane * 8;
        async_copy16(gg, Gb + w * 512);
    }

    // Reg-stage X tile (128x64 f32), convert, swizzled LDS writes.
    const float* xh = x + ((size_t)head * TDIM + ch * 128) * DDIM;
#pragma unroll
    for (int e = 0; e < 4; ++e) {
        const int i4 = e * 512 + tid;            // f4 index in 128x64 tile
        const int r  = i4 >> 4;                  // 0..127
        const int c4 = (i4 & 15) << 2;
        const f4 v = *reinterpret_cast<const f4*>(xh + (size_t)i4 * 4);
        s4 pk;
        pk[0] = f2bf(v[0]); pk[1] = f2bf(v[1]);
        pk[2] = f2bf(v[2]); pk[3] = f2bf(v[3]);
        *(s4*)((char*)Xb + r * 128 + ((2 * c4) ^ ((r & 7) << 4))) = pk;
    }
    __syncthreads();   // drains G DMA (vmcnt) + Xb writes (lgkmcnt)

    // MFMA: wave w owns rows w*16..w*16+15 x 4 col-tiles, K=64.
    const int li = lane & 15, g = lane >> 4;

    f32x4 acc[4];
#pragma unroll
    for (int d = 0; d < 4; ++d) acc[d] = (f32x4){0.f, 0.f, 0.f, 0.f};

#pragma unroll
    for (int k0 = 0; k0 < 64; k0 += 32) {
        bf16x8 af, bv[4];
        af = *fragp(Xb, w * 16 + li, 64, k0 + 8 * g);
#pragma unroll
        for (int d = 0; d < 4; ++d)
            bv[d] = *fragp(Gb, d * 16 + li, 64, k0 + 8 * g);
#pragma unroll
        for (int d = 0; d < 4; ++d)
            acc[d] = __builtin_amdgcn_mfma_f32_16x16x32_bf16(
                af, bv[d], acc[d], 0, 0, 0);
    }

    float* oh = out + ((size_t)head * TDIM + ch * 128) * DDIM;
#pragma unroll
    for (int d = 0; d < 4; ++d)
#pragma unroll
        for (int q = 0; q < 4; ++q)
            oh[(w * 16 + g * 4 + q) * 64 + d * 16 + li] = acc[d][q];
}

extern "C" void kernel_launch(void* const* d_in, const int* in_sizes, int n_in,
                              void* d_out, int out_size, void* d_ws, size_t ws_size,
                              hipStream_t stream) {
    const float* x = (const float*)d_in[0];
    float* out  = (float*)d_out;
    short* part = (short*)d_ws;                          // 512*8 KB = 4.2 MB
    short* gbf  = part + (size_t)512 * 4096;             // 256 KB

    k1_gram<<<NHEADS * NCH, 256, 0, stream>>>(x, part);
    k2a_reduce<<<128, 256, 0, stream>>>(part, gbf);
    k2b_xg<<<512, 512, 0, stream>>>(x, out, gbf);
}